// Round 4
// baseline (2283.083 us; speedup 1.0000x reference)
//
#include <hip/hip_runtime.h>

typedef unsigned short u16;
typedef __attribute__((ext_vector_type(8))) __bf16 bf16x8;
typedef __attribute__((ext_vector_type(4))) float f32x4;

#define NF    39
#define NNUM  13
#define NCAT  26
#define VOC   100000
#define NPAIR 741
#define KHID  23712   /* 2*741*16 */
#define BATCH 4096
#define HD1   1024
#define HD2   512
#define HD3   256

__device__ __forceinline__ u16 f2bf(float f) {
  unsigned u = __builtin_bit_cast(unsigned, f);
  return (u16)((u + 0x7fffu + ((u >> 16) & 1u)) >> 16);   // RNE
}

__device__ __forceinline__ void gload16(const void* g, void* l) {
  __builtin_amdgcn_global_load_lds((const __attribute__((address_space(1))) void*)g,
                                   (__attribute__((address_space(3))) void*)l, 16, 0, 0);
}

// ---------------------------------------------------------------------------
// Front end: gather + SE + bilinear proj + pairwise products -> hid bf16 [B][23712]
// ---------------------------------------------------------------------------
__global__ __launch_bounds__(256) void fuse_front(
    const int* __restrict__ cat, const float* __restrict__ num,
    const float* __restrict__ tables, const float* __restrict__ nemb,
    const float* __restrict__ Wse1, const float* __restrict__ Wse2,
    const float* __restrict__ Wbil, u16* __restrict__ hid)
{
  __shared__ float xs[NF][16];
  __shared__ float wb[NF][16][16];   // [f][e][d]
  __shared__ float pr[NF][16];       // proj
  __shared__ float Zs[NF], Ts[NNUM], As[NF];
  __shared__ unsigned char pis[NPAIR], pjs[NPAIR];

  const int b = blockIdx.x;
  const int tid = threadIdx.x;

  for (int i = tid; i < NF * 256; i += 256) ((float*)wb)[i] = Wbil[i];

  for (int t = tid; t < NNUM * 16; t += 256) {
    int f = t >> 4, e = t & 15;
    xs[f][e] = num[b * NNUM + f] * nemb[t];
  }
  for (int t = tid; t < NCAT * 16; t += 256) {
    int c = t >> 4, e = t & 15;
    int cv = cat[b * NCAT + c];
    xs[NNUM + c][e] = tables[((size_t)c * VOC + cv) * 16 + e];
  }
  for (int p = tid; p < NPAIR; p += 256) {
    int i = 0, rs = 0;
    while (p >= rs + (NF - 1 - i)) { rs += NF - 1 - i; ++i; }
    pis[p] = (unsigned char)i;
    pjs[p] = (unsigned char)(i + 1 + (p - rs));
  }
  __syncthreads();

  if (tid < NF) {
    float s = 0.f;
    #pragma unroll
    for (int e = 0; e < 16; ++e) s += xs[tid][e];
    Zs[tid] = s * (1.f / 16.f);
  }
  __syncthreads();
  if (tid < NNUM) {
    float s = 0.f;
    for (int f = 0; f < NF; ++f) s += Zs[f] * Wse1[f * NNUM + tid];
    Ts[tid] = fmaxf(s, 0.f);
  }
  __syncthreads();
  if (tid < NF) {
    float s = 0.f;
    for (int r = 0; r < NNUM; ++r) s += Ts[r] * Wse2[r * NF + tid];
    As[tid] = fmaxf(s, 0.f);
  }
  for (int t = tid; t < NF * 16; t += 256) {
    int f = t >> 4, d = t & 15;
    float s = 0.f;
    #pragma unroll
    for (int e = 0; e < 16; ++e) s += xs[f][e] * wb[f][e][d];
    pr[f][d] = s;
  }
  __syncthreads();

  u16* hr = hid + (size_t)b * KHID;
  for (int idx = tid; idx < NPAIR * 16; idx += 256) {
    int p = idx >> 4, e = idx & 15;
    int i = pis[p], j = pjs[p];
    float bv = pr[i][e] * xs[j][e];
    hr[NPAIR * 16 + idx] = f2bf(bv);
    hr[idx] = f2bf(As[i] * As[j] * bv);
  }
}

// ---------------------------------------------------------------------------
// Transpose + cast: in f32 [K][N] -> out bf16 [N][K]
// ---------------------------------------------------------------------------
__global__ __launch_bounds__(256) void transpose_cast(
    const float* __restrict__ in, u16* __restrict__ out, int K, int N)
{
  __shared__ float t[32][33];
  const int k0 = blockIdx.x * 32, n0 = blockIdx.y * 32;
  const int c = threadIdx.x & 31, r = threadIdx.x >> 5;
  #pragma unroll
  for (int it = 0; it < 4; ++it)
    t[r + it * 8][c] = in[(size_t)(k0 + r + it * 8) * N + n0 + c];
  __syncthreads();
  #pragma unroll
  for (int it = 0; it < 4; ++it)
    out[(size_t)(n0 + r + it * 8) * K + k0 + c] = f2bf(t[c][r + it * 8]);
}

// ---------------------------------------------------------------------------
// Variant A (fallback, 1 block/CU): 256x256, 4-slot ring, depth-3 prefetch.
// ---------------------------------------------------------------------------
__global__ __launch_bounds__(512, 2) void gemm8_bf16(
    const u16* __restrict__ A, const u16* __restrict__ Bt,
    float* __restrict__ Cp, int M, int N, int K, int totku, int kpb)
{
  __shared__ __align__(16) u16 lds[4 * 16384];   // 128 KiB

  const int tid = threadIdx.x;
  const int wid = tid >> 6, lane = tid & 63;

  const int d = blockIdx.x;
  const int half = d >> 7, r_ = d & 127;
  const int wg = (r_ & 7) * 16 + half * 128 + (r_ >> 3);
  const int mb = wg & 15, nb = (wg >> 4) & 3, sb = wg >> 6;

  const int ks0 = sb * kpb;
  const int kunits = (totku - ks0 < kpb) ? (totku - ks0) : kpb;

  const int wm = wid >> 2, wn = wid & 3;
  const int lrow = lane & 15, c0 = lane >> 4;

  const int rA = tid >> 2;
  const int csrc = (tid & 3) ^ ((rA >> 1) & 3);
  const u16* pA = A  + (size_t)((size_t)mb * 256 + rA) * K + (size_t)ks0 * 32 + csrc * 8;
  const u16* pB = Bt + (size_t)((size_t)nb * 256 + rA) * K + (size_t)ks0 * 32 + csrc * 8;
  const size_t rowskip = (size_t)128 * K;
  u16* dA = lds + wid * 512;
  u16* dB = lds + 8192 + wid * 512;

  int offA[8], offB[4];
  #pragma unroll
  for (int m = 0; m < 8; ++m) {
    int r = wm * 128 + m * 16 + lrow;
    offA[m] = r * 32 + ((c0 ^ ((r >> 1) & 3)) << 3);
  }
  #pragma unroll
  for (int n = 0; n < 4; ++n) {
    int r = wn * 64 + n * 16 + lrow;
    offB[n] = 8192 + r * 32 + ((c0 ^ ((r >> 1) & 3)) << 3);
  }

  f32x4 acc[8][4];
  #pragma unroll
  for (int m = 0; m < 8; ++m)
    #pragma unroll
    for (int n = 0; n < 4; ++n) acc[m][n] = f32x4{0.f, 0.f, 0.f, 0.f};

  #pragma unroll
  for (int u = 0; u < 3; ++u) {
    const u16* a = pA + u * 32;
    const u16* b = pB + u * 32;
    u16* da = dA + u * 16384;
    u16* db = dB + u * 16384;
    gload16(a, da);            gload16(a + rowskip, da + 4096);
    gload16(b, db);            gload16(b + rowskip, db + 4096);
  }

  for (int t = 0; t < kunits; ++t) {
    asm volatile("s_waitcnt vmcnt(8)" ::: "memory");
    __builtin_amdgcn_s_barrier();
    __builtin_amdgcn_sched_barrier(0);

    {
      int su = (t + 3 < kunits) ? (t + 3) : (kunits - 1);
      const u16* a = pA + (size_t)su * 32;
      const u16* b = pB + (size_t)su * 32;
      int so = ((t + 3) & 3) * 16384;
      u16* da = dA + so;
      u16* db = dB + so;
      gload16(a, da);          gload16(a + rowskip, da + 4096);
      gload16(b, db);          gload16(b + rowskip, db + 4096);
    }

    const u16* sl = lds + (t & 3) * 16384;
    bf16x8 af[8], bg[4];
    #pragma unroll
    for (int m = 0; m < 8; ++m) af[m] = *reinterpret_cast<const bf16x8*>(sl + offA[m]);
    #pragma unroll
    for (int n = 0; n < 4; ++n) bg[n] = *reinterpret_cast<const bf16x8*>(sl + offB[n]);

    __builtin_amdgcn_s_setprio(1);
    #pragma unroll
    for (int m = 0; m < 8; ++m)
      #pragma unroll
      for (int n = 0; n < 4; ++n)
        acc[m][n] = __builtin_amdgcn_mfma_f32_16x16x32_bf16(af[m], bg[n], acc[m][n], 0, 0, 0);
    __builtin_amdgcn_s_setprio(0);

    __builtin_amdgcn_sched_barrier(0);
    __builtin_amdgcn_s_barrier();
  }

  float* C = Cp + (size_t)sb * M * N;
  #pragma unroll
  for (int m = 0; m < 8; ++m) {
    const int rb = mb * 256 + wm * 128 + m * 16 + (lane >> 4) * 4;
    #pragma unroll
    for (int n = 0; n < 4; ++n) {
      const int col = nb * 256 + wn * 64 + n * 16 + (lane & 15);
      #pragma unroll
      for (int j = 0; j < 4; ++j)
        __builtin_nontemporal_store(acc[m][n][j], &C[(size_t)(rb + j) * N + col]);
    }
  }
}

// ---------------------------------------------------------------------------
// Variant B (2 blocks/CU): 256x256, 2-slot ring (64 KB LDS), depth-1 prefetch,
// counted vmcnt(4) never 0; cross-block overlap supplies latency hiding.
// Phase: vmcnt(4); bar; 12 ds_read; lgkm(0); bar(all reads done);
//        stage unit t+2 into just-freed slot || 32 MFMA (setprio).
// ---------------------------------------------------------------------------
__global__ __launch_bounds__(512, 4) void gemm8v2_bf16(
    const u16* __restrict__ A, const u16* __restrict__ Bt,
    float* __restrict__ Cp, int M, int N, int K, int totku, int kpb)
{
  __shared__ __align__(16) u16 lds[2 * 16384];   // 64 KiB

  const int tid = threadIdx.x;
  const int wid = tid >> 6, lane = tid & 63;

  // T1 bijective swizzle for 512 blocks: XCD x gets 4 chunks of 16 consecutive
  // wg (each chunk = one (nb,sb) B-strip, L2-shared).
  const int d = blockIdx.x;
  const int x = d & 7, j = d >> 3;            // x: XCD, j in [0,64)
  const int wg = (j >> 4) * 128 + x * 16 + (j & 15);
  const int mb = wg & 15, nb = (wg >> 4) & 3, sb = wg >> 6;   // sb in [0,8)

  const int ks0 = sb * kpb;
  const int kunits = (totku - ks0 < kpb) ? (totku - ks0) : kpb;

  const int wm = wid >> 2, wn = wid & 3;
  const int lrow = lane & 15, c0 = lane >> 4;

  const int rA = tid >> 2;
  const int csrc = (tid & 3) ^ ((rA >> 1) & 3);
  const u16* pA = A  + (size_t)((size_t)mb * 256 + rA) * K + (size_t)ks0 * 32 + csrc * 8;
  const u16* pB = Bt + (size_t)((size_t)nb * 256 + rA) * K + (size_t)ks0 * 32 + csrc * 8;
  const size_t rowskip = (size_t)128 * K;
  u16* dA = lds + wid * 512;
  u16* dB = lds + 8192 + wid * 512;

  int offA[8], offB[4];
  #pragma unroll
  for (int m = 0; m < 8; ++m) {
    int r = wm * 128 + m * 16 + lrow;
    offA[m] = r * 32 + ((c0 ^ ((r >> 1) & 3)) << 3);
  }
  #pragma unroll
  for (int n = 0; n < 4; ++n) {
    int r = wn * 64 + n * 16 + lrow;
    offB[n] = 8192 + r * 32 + ((c0 ^ ((r >> 1) & 3)) << 3);
  }

  f32x4 acc[8][4];
  #pragma unroll
  for (int m = 0; m < 8; ++m)
    #pragma unroll
    for (int n = 0; n < 4; ++n) acc[m][n] = f32x4{0.f, 0.f, 0.f, 0.f};

  // prologue: stage units 0,1 into slots 0,1 (8 loads/thread in flight)
  #pragma unroll
  for (int u = 0; u < 2; ++u) {
    const u16* a = pA + u * 32;
    const u16* b = pB + u * 32;
    u16* da = dA + u * 16384;
    u16* db = dB + u * 16384;
    gload16(a, da);            gload16(a + rowskip, da + 4096);
    gload16(b, db);            gload16(b + rowskip, db + 4096);
  }

  for (int t = 0; t < kunits; ++t) {
    // in flight: units t, t+1 (8 loads) -> wait oldest 4 (unit t), keep 4
    asm volatile("s_waitcnt vmcnt(4)" ::: "memory");
    __builtin_amdgcn_s_barrier();
    __builtin_amdgcn_sched_barrier(0);

    const u16* sl = lds + (t & 1) * 16384;
    bf16x8 af[8], bg[4];
    #pragma unroll
    for (int m = 0; m < 8; ++m) af[m] = *reinterpret_cast<const bf16x8*>(sl + offA[m]);
    #pragma unroll
    for (int n = 0; n < 4; ++n) bg[n] = *reinterpret_cast<const bf16x8*>(sl + offB[n]);
    asm volatile("s_waitcnt lgkmcnt(0)" ::: "memory");
    __builtin_amdgcn_sched_barrier(0);
    __builtin_amdgcn_s_barrier();          // all waves' reads of slot t&1 done

    // stage unit t+2 into slot t&1 (now dead); overlaps with MFMA below
    {
      int su = (t + 2 < kunits) ? (t + 2) : (kunits - 1);
      const u16* a = pA + (size_t)su * 32;
      const u16* b = pB + (size_t)su * 32;
      int so = (t & 1) * 16384;
      u16* da = dA + so;
      u16* db = dB + so;
      gload16(a, da);          gload16(a + rowskip, da + 4096);
      gload16(b, db);          gload16(b + rowskip, db + 4096);
    }

    __builtin_amdgcn_s_setprio(1);
    #pragma unroll
    for (int m = 0; m < 8; ++m)
      #pragma unroll
      for (int n = 0; n < 4; ++n)
        acc[m][n] = __builtin_amdgcn_mfma_f32_16x16x32_bf16(af[m], bg[n], acc[m][n], 0, 0, 0);
    __builtin_amdgcn_s_setprio(0);
    __builtin_amdgcn_sched_barrier(0);
  }

  float* C = Cp + (size_t)sb * M * N;
  #pragma unroll
  for (int m = 0; m < 8; ++m) {
    const int rb = mb * 256 + wm * 128 + m * 16 + (lane >> 4) * 4;
    #pragma unroll
    for (int n = 0; n < 4; ++n) {
      const int col = nb * 256 + wn * 64 + n * 16 + (lane & 15);
      #pragma unroll
      for (int j = 0; j < 4; ++j)
        __builtin_nontemporal_store(acc[m][n][j], &C[(size_t)(rb + j) * N + col]);
    }
  }
}

// ---------------------------------------------------------------------------
// 128x128 m97-structure GEMM for the small layers 2/3
// ---------------------------------------------------------------------------
__global__ __launch_bounds__(256) void gemm_bf16(
    const u16* __restrict__ A, const u16* __restrict__ Bt,
    float* __restrict__ Cp, int M, int N, int K, int kps)
{
  __shared__ __align__(16) u16 lA[128 * 32];
  __shared__ __align__(16) u16 lB[128 * 32];
  const int tid = threadIdx.x;
  const int mb = blockIdx.x, nb = blockIdx.y, sb = blockIdx.z;
  const int w = tid >> 6, lane = tid & 63;
  const int wr = (w >> 1) * 64, wc = (w & 1) * 64;
  const int lrow = lane & 15, lko = (lane >> 4) * 8;

  f32x4 acc[4][4];
  #pragma unroll
  for (int m = 0; m < 4; ++m)
    #pragma unroll
    for (int n = 0; n < 4; ++n) acc[m][n] = f32x4{0.f, 0.f, 0.f, 0.f};

  const u16* Ab = A + (size_t)mb * 128 * K;
  const u16* Bb = Bt + (size_t)nb * 128 * K;
  const int r0 = tid >> 2, inn = (tid & 3) * 8;
  const int l0 = (tid & ~63) * 8, l1 = ((256 + tid) & ~63) * 8;

  const int ks1 = (sb + 1) * kps;
  for (int ks = sb * kps; ks < ks1; ++ks) {
    const int k0 = ks * 32;
    __syncthreads();
    gload16(Ab + (size_t)r0 * K + k0 + inn,        lA + l0);
    gload16(Ab + (size_t)(r0 + 64) * K + k0 + inn, lA + l1);
    gload16(Bb + (size_t)r0 * K + k0 + inn,        lB + l0);
    gload16(Bb + (size_t)(r0 + 64) * K + k0 + inn, lB + l1);
    __syncthreads();
    bf16x8 af[4], bg[4];
    #pragma unroll
    for (int m = 0; m < 4; ++m)
      af[m] = *reinterpret_cast<const bf16x8*>(&lA[(wr + m * 16 + lrow) * 32 + lko]);
    #pragma unroll
    for (int n = 0; n < 4; ++n)
      bg[n] = *reinterpret_cast<const bf16x8*>(&lB[(wc + n * 16 + lrow) * 32 + lko]);
    #pragma unroll
    for (int m = 0; m < 4; ++m)
      #pragma unroll
      for (int n = 0; n < 4; ++n)
        acc[m][n] = __builtin_amdgcn_mfma_f32_16x16x32_bf16(af[m], bg[n], acc[m][n], 0, 0, 0);
  }

  float* C = Cp + (size_t)sb * M * N;
  #pragma unroll
  for (int m = 0; m < 4; ++m) {
    const int rb = mb * 128 + wr + m * 16 + (lane >> 4) * 4;
    #pragma unroll
    for (int n = 0; n < 4; ++n) {
      const int col = nb * 128 + wc + n * 16 + (lane & 15);
      #pragma unroll
      for (int j = 0; j < 4; ++j)
        __builtin_nontemporal_store(acc[m][n][j], &C[(size_t)(rb + j) * N + col]);
    }
  }
}

// ---------------------------------------------------------------------------
// Split-K reduce + bias + relu (+ cast); NT loads on the partial stream
// ---------------------------------------------------------------------------
__global__ __launch_bounds__(256) void reduce_bias_relu_bf16(
    const float* __restrict__ part, int S, size_t MN,
    const float* __restrict__ bias, int nmask, u16* __restrict__ out)
{
  for (size_t i = blockIdx.x * 256ull + threadIdx.x; i < MN; i += (size_t)gridDim.x * 256) {
    float s = 0.f;
    for (int k = 0; k < S; ++k) s += __builtin_nontemporal_load(&part[(size_t)k * MN + i]);
    s += bias[i & nmask];
    out[i] = f2bf(fmaxf(s, 0.f));
  }
}

__global__ __launch_bounds__(256) void reduce_bias_relu_f32(
    const float* __restrict__ part, int S, size_t MN,
    const float* __restrict__ bias, int nmask, float* __restrict__ out)
{
  for (size_t i = blockIdx.x * 256ull + threadIdx.x; i < MN; i += (size_t)gridDim.x * 256) {
    float s = 0.f;
    for (int k = 0; k < S; ++k) s += __builtin_nontemporal_load(&part[(size_t)k * MN + i]);
    s += bias[i & nmask];
    out[i] = fmaxf(s, 0.f);
  }
}

// ---------------------------------------------------------------------------
// Final: out[b] = h3[b,:] . W_out + b_out   (one wave per row)
// ---------------------------------------------------------------------------
__global__ __launch_bounds__(256) void final_dot(
    const float* __restrict__ h3, const float* __restrict__ Wout,
    const float* __restrict__ bout, float* __restrict__ out)
{
  const int row = blockIdx.x * 4 + (threadIdx.x >> 6);
  const int lane = threadIdx.x & 63;
  const float* hr = h3 + (size_t)row * HD3;
  float s = 0.f;
  #pragma unroll
  for (int i = 0; i < 4; ++i) s += hr[lane + i * 64] * Wout[lane + i * 64];
  #pragma unroll
  for (int off = 32; off; off >>= 1) s += __shfl_down(s, off, 64);
  if (lane == 0) out[row] = s + bout[0];
}

// ---------------------------------------------------------------------------
extern "C" void kernel_launch(void* const* d_in, const int* in_sizes, int n_in,
                              void* d_out, int out_size, void* d_ws, size_t ws_size,
                              hipStream_t stream)
{
  const int*   cat    = (const int*)  d_in[0];
  const float* num    = (const float*)d_in[1];
  const float* tables = (const float*)d_in[2];
  const float* nemb   = (const float*)d_in[3];
  const float* Wse1   = (const float*)d_in[4];
  const float* Wse2   = (const float*)d_in[5];
  const float* Wbil   = (const float*)d_in[6];
  const float* Wd1    = (const float*)d_in[7];
  const float* bd1    = (const float*)d_in[8];
  const float* Wd2    = (const float*)d_in[9];
  const float* bd2    = (const float*)d_in[10];
  const float* Wd3    = (const float*)d_in[11];
  const float* bd3    = (const float*)d_in[12];
  const float* Wout   = (const float*)d_in[13];
  const float* bout   = (const float*)d_in[14];

  // big layout needs: hid(194,248,704) + W1t(48,562,176) + part(134,217,728)
  //                   + W2t(1,048,576) + W3t(262,144) = 378,339,328
  const bool big = ws_size >= 378339328ull;   // constant per harness -> deterministic

  char* ws = (char*)d_ws;
  u16*   hid  = (u16*)  (ws + 0ull);
  u16*   W1t  = (u16*)  (ws + 194248704ull);
  float* part = (float*)(ws + 242810880ull);
  u16*   W2t  = (u16*)  (ws + (big ? 377028608ull : 309919744ull));
  u16*   W3t  = (u16*)  (ws + (big ? 378077184ull : 310968320ull));
  // dead-hid region reuse (hid consumed by gemm1 before these are written):
  u16*   h1b  = (u16*)  (ws + 0ull);
  u16*   h2b  = (u16*)  (ws + 8388608ull);
  float* h3f  = (float*)(ws + 12582912ull);

  transpose_cast<<<dim3(KHID / 32, HD1 / 32), 256, 0, stream>>>(Wd1, W1t, KHID, HD1);
  transpose_cast<<<dim3(HD1 / 32, HD2 / 32), 256, 0, stream>>>(Wd2, W2t, HD1, HD2);
  transpose_cast<<<dim3(HD2 / 32, HD3 / 32), 256, 0, stream>>>(Wd3, W3t, HD2, HD3);
  fuse_front<<<BATCH, 256, 0, stream>>>(cat, num, tables, nemb, Wse1, Wse2, Wbil, hid);

  // layer 1: [4096 x 23712] @ [23712 x 1024]
  if (big) {
    // 2 blocks/CU variant: split-K=8 (93x7 + 90), grid 512
    gemm8v2_bf16<<<512, 512, 0, stream>>>(hid, W1t, part, BATCH, HD1, KHID, 741, 93);
    reduce_bias_relu_bf16<<<2048, 256, 0, stream>>>(part, 8, (size_t)BATCH * HD1, bd1, HD1 - 1, h1b);
  } else {
    // fallback: 1 block/CU, split-K=4 (186x3 + 183), grid 256
    gemm8_bf16<<<256, 512, 0, stream>>>(hid, W1t, part, BATCH, HD1, KHID, 741, 186);
    reduce_bias_relu_bf16<<<2048, 256, 0, stream>>>(part, 4, (size_t)BATCH * HD1, bd1, HD1 - 1, h1b);
  }

  // layer 2: [4096 x 1024] @ [1024 x 512], split-K=2 (32 = 2*16)
  gemm_bf16<<<dim3(BATCH / 128, HD2 / 128, 2), 256, 0, stream>>>(h1b, W2t, part, BATCH, HD2, HD1, 16);
  reduce_bias_relu_bf16<<<2048, 256, 0, stream>>>(part, 2, (size_t)BATCH * HD2, bd2, HD2 - 1, h2b);

  // layer 3: [4096 x 512] @ [512 x 256], split-K=4 (16 = 4*4)
  gemm_bf16<<<dim3(BATCH / 128, HD3 / 128, 4), 256, 0, stream>>>(h2b, W3t, part, BATCH, HD3, HD2, 4);
  reduce_bias_relu_f32<<<2048, 256, 0, stream>>>(part, 4, (size_t)BATCH * HD3, bd3, HD3 - 1, h3f);

  final_dot<<<BATCH / 4, 256, 0, stream>>>(h3f, Wout, bout, (float*)d_out);
}

// Round 5
// 398.765 us; speedup vs baseline: 5.7254x; 5.7254x over previous
//
#include <hip/hip_runtime.h>

typedef unsigned short u16;
typedef __attribute__((ext_vector_type(8))) __bf16 bf16x8;
typedef __attribute__((ext_vector_type(4))) float f32x4;

#define NF    39
#define NNUM  13
#define NCAT  26
#define VOC   100000
#define NPAIR 741
#define KHID  23712   /* 2*741*16 */
#define BATCH 4096
#define HD1   1024
#define HD2   512
#define HD3   256

__device__ __forceinline__ u16 f2bf(float f) {
  unsigned u = __builtin_bit_cast(unsigned, f);
  return (u16)((u + 0x7fffu + ((u >> 16) & 1u)) >> 16);   // RNE
}

__device__ __forceinline__ void gload16(const void* g, void* l) {
  __builtin_amdgcn_global_load_lds((const __attribute__((address_space(1))) void*)g,
                                   (__attribute__((address_space(3))) void*)l, 16, 0, 0);
}

// ---------------------------------------------------------------------------
// Front end: gather + SE + bilinear proj + pairwise products -> hid bf16 [B][23712]
// ---------------------------------------------------------------------------
__global__ __launch_bounds__(256) void fuse_front(
    const int* __restrict__ cat, const float* __restrict__ num,
    const float* __restrict__ tables, const float* __restrict__ nemb,
    const float* __restrict__ Wse1, const float* __restrict__ Wse2,
    const float* __restrict__ Wbil, u16* __restrict__ hid)
{
  __shared__ float xs[NF][16];
  __shared__ float wb[NF][16][16];   // [f][e][d]
  __shared__ float pr[NF][16];       // proj
  __shared__ float Zs[NF], Ts[NNUM], As[NF];
  __shared__ unsigned char pis[NPAIR], pjs[NPAIR];

  const int b = blockIdx.x;
  const int tid = threadIdx.x;

  for (int i = tid; i < NF * 256; i += 256) ((float*)wb)[i] = Wbil[i];

  for (int t = tid; t < NNUM * 16; t += 256) {
    int f = t >> 4, e = t & 15;
    xs[f][e] = num[b * NNUM + f] * nemb[t];
  }
  for (int t = tid; t < NCAT * 16; t += 256) {
    int c = t >> 4, e = t & 15;
    int cv = cat[b * NCAT + c];
    xs[NNUM + c][e] = tables[((size_t)c * VOC + cv) * 16 + e];
  }
  for (int p = tid; p < NPAIR; p += 256) {
    int i = 0, rs = 0;
    while (p >= rs + (NF - 1 - i)) { rs += NF - 1 - i; ++i; }
    pis[p] = (unsigned char)i;
    pjs[p] = (unsigned char)(i + 1 + (p - rs));
  }
  __syncthreads();

  if (tid < NF) {
    float s = 0.f;
    #pragma unroll
    for (int e = 0; e < 16; ++e) s += xs[tid][e];
    Zs[tid] = s * (1.f / 16.f);
  }
  __syncthreads();
  if (tid < NNUM) {
    float s = 0.f;
    for (int f = 0; f < NF; ++f) s += Zs[f] * Wse1[f * NNUM + tid];
    Ts[tid] = fmaxf(s, 0.f);
  }
  __syncthreads();
  if (tid < NF) {
    float s = 0.f;
    for (int r = 0; r < NNUM; ++r) s += Ts[r] * Wse2[r * NF + tid];
    As[tid] = fmaxf(s, 0.f);
  }
  for (int t = tid; t < NF * 16; t += 256) {
    int f = t >> 4, d = t & 15;
    float s = 0.f;
    #pragma unroll
    for (int e = 0; e < 16; ++e) s += xs[f][e] * wb[f][e][d];
    pr[f][d] = s;
  }
  __syncthreads();

  u16* hr = hid + (size_t)b * KHID;
  for (int idx = tid; idx < NPAIR * 16; idx += 256) {
    int p = idx >> 4, e = idx & 15;
    int i = pis[p], j = pjs[p];
    float bv = pr[i][e] * xs[j][e];
    hr[NPAIR * 16 + idx] = f2bf(bv);
    hr[idx] = f2bf(As[i] * As[j] * bv);
  }
}

// ---------------------------------------------------------------------------
// Transpose + cast: in f32 [K][N] -> out bf16 [N][K]
// ---------------------------------------------------------------------------
__global__ __launch_bounds__(256) void transpose_cast(
    const float* __restrict__ in, u16* __restrict__ out, int K, int N)
{
  __shared__ float t[32][33];
  const int k0 = blockIdx.x * 32, n0 = blockIdx.y * 32;
  const int c = threadIdx.x & 31, r = threadIdx.x >> 5;
  #pragma unroll
  for (int it = 0; it < 4; ++it)
    t[r + it * 8][c] = in[(size_t)(k0 + r + it * 8) * N + n0 + c];
  __syncthreads();
  #pragma unroll
  for (int it = 0; it < 4; ++it)
    out[(size_t)(n0 + r + it * 8) * K + k0 + c] = f2bf(t[c][r + it * 8]);
}

// ---------------------------------------------------------------------------
// 256x256 8-wave pipelined bf16 GEMM. T1 XCD swizzle + T2 LDS swizzle +
// T3/T4 counted vmcnt 4-slot ring (depth-3) + T5 setprio.
// ONE barrier per phase: at barrier(t), every wave has data-complete its
// phase-(t-1) ds_reads (lgkm wait precedes its MFMAs, which precede the
// barrier), so staging into slot (t+3)&3 == (t-1)&3 after the barrier is
// race-free; vmcnt(8) before the barrier proves slot t&3 fully arrived.
// ---------------------------------------------------------------------------
__global__ __launch_bounds__(512, 2) void gemm8_bf16(
    const u16* __restrict__ A, const u16* __restrict__ Bt,
    float* __restrict__ Cp, int M, int N, int K, int totku, int kpb)
{
  __shared__ __align__(16) u16 lds[4 * 16384];   // 128 KiB

  const int tid = threadIdx.x;
  const int wid = tid >> 6, lane = tid & 63;

  // T1: bijective XCD swizzle for 256 blocks; XCD x gets 2 chunks of 16
  // consecutive wg (each chunk = one (nb,sb) B-strip, L2-shared).
  const int d = blockIdx.x;
  const int half = d >> 7, r_ = d & 127;
  const int wg = (r_ & 7) * 16 + half * 128 + (r_ >> 3);
  const int mb = wg & 15, nb = (wg >> 4) & 3, sb = wg >> 6;

  const int ks0 = sb * kpb;
  const int kunits = (totku - ks0 < kpb) ? (totku - ks0) : kpb;

  const int wm = wid >> 2, wn = wid & 3;        // 2M x 4N waves
  const int lrow = lane & 15, c0 = lane >> 4;

  // staging addresses (inverse-swizzled global source, linear LDS dest)
  const int rA = tid >> 2;
  const int csrc = (tid & 3) ^ ((rA >> 1) & 3);
  const u16* pA = A  + (size_t)((size_t)mb * 256 + rA) * K + (size_t)ks0 * 32 + csrc * 8;
  const u16* pB = Bt + (size_t)((size_t)nb * 256 + rA) * K + (size_t)ks0 * 32 + csrc * 8;
  const size_t rowskip = (size_t)128 * K;
  u16* dA = lds + wid * 512;
  u16* dB = lds + 8192 + wid * 512;

  // swizzled read offsets (loop-invariant per lane)
  int offA[8], offB[4];
  #pragma unroll
  for (int m = 0; m < 8; ++m) {
    int r = wm * 128 + m * 16 + lrow;
    offA[m] = r * 32 + ((c0 ^ ((r >> 1) & 3)) << 3);
  }
  #pragma unroll
  for (int n = 0; n < 4; ++n) {
    int r = wn * 64 + n * 16 + lrow;
    offB[n] = 8192 + r * 32 + ((c0 ^ ((r >> 1) & 3)) << 3);
  }

  f32x4 acc[8][4];
  #pragma unroll
  for (int m = 0; m < 8; ++m)
    #pragma unroll
    for (int n = 0; n < 4; ++n) acc[m][n] = f32x4{0.f, 0.f, 0.f, 0.f};

  // prologue: stage units 0,1,2 into slots 0,1,2 (12 loads/thread in flight)
  #pragma unroll
  for (int u = 0; u < 3; ++u) {
    const u16* a = pA + u * 32;
    const u16* b = pB + u * 32;
    u16* da = dA + u * 16384;
    u16* db = dB + u * 16384;
    gload16(a, da);            gload16(a + rowskip, da + 4096);
    gload16(b, db);            gload16(b + rowskip, db + 4096);
  }

  for (int t = 0; t < kunits; ++t) {
    // in flight: units t,t+1,t+2 (12 loads) -> wait oldest 4 (unit t), keep 8
    asm volatile("s_waitcnt vmcnt(8)" ::: "memory");
    __builtin_amdgcn_s_barrier();
    __builtin_amdgcn_sched_barrier(0);

    // stage unit t+3 into slot (t+3)&3 == (t-1)&3 (read-complete by barrier)
    {
      int su = (t + 3 < kunits) ? (t + 3) : (kunits - 1);
      const u16* a = pA + (size_t)su * 32;
      const u16* b = pB + (size_t)su * 32;
      int so = ((t + 3) & 3) * 16384;
      u16* da = dA + so;
      u16* db = dB + so;
      gload16(a, da);          gload16(a + rowskip, da + 4096);
      gload16(b, db);          gload16(b + rowskip, db + 4096);
    }

    const u16* sl = lds + (t & 3) * 16384;
    bf16x8 af[8], bg[4];
    #pragma unroll
    for (int m = 0; m < 8; ++m) af[m] = *reinterpret_cast<const bf16x8*>(sl + offA[m]);
    #pragma unroll
    for (int n = 0; n < 4; ++n) bg[n] = *reinterpret_cast<const bf16x8*>(sl + offB[n]);

    __builtin_amdgcn_s_setprio(1);
    #pragma unroll
    for (int m = 0; m < 8; ++m)
      #pragma unroll
      for (int n = 0; n < 4; ++n)
        acc[m][n] = __builtin_amdgcn_mfma_f32_16x16x32_bf16(af[m], bg[n], acc[m][n], 0, 0, 0);
    __builtin_amdgcn_s_setprio(0);

    __builtin_amdgcn_sched_barrier(0);
    // no trailing barrier: next phase's barrier provides the cross-wave sync
  }

  // epilogue: write f32 partials (NT: keep the partial stream out of L2/L3)
  float* C = Cp + (size_t)sb * M * N;
  #pragma unroll
  for (int m = 0; m < 8; ++m) {
    const int rb = mb * 256 + wm * 128 + m * 16 + (lane >> 4) * 4;
    #pragma unroll
    for (int n = 0; n < 4; ++n) {
      const int col = nb * 256 + wn * 64 + n * 16 + (lane & 15);
      #pragma unroll
      for (int j = 0; j < 4; ++j)
        __builtin_nontemporal_store(acc[m][n][j], &C[(size_t)(rb + j) * N + col]);
    }
  }
}

// ---------------------------------------------------------------------------
// 128x128 m97-structure GEMM for the small layers 2/3
// ---------------------------------------------------------------------------
__global__ __launch_bounds__(256) void gemm_bf16(
    const u16* __restrict__ A, const u16* __restrict__ Bt,
    float* __restrict__ Cp, int M, int N, int K, int kps)
{
  __shared__ __align__(16) u16 lA[128 * 32];
  __shared__ __align__(16) u16 lB[128 * 32];
  const int tid = threadIdx.x;
  const int mb = blockIdx.x, nb = blockIdx.y, sb = blockIdx.z;
  const int w = tid >> 6, lane = tid & 63;
  const int wr = (w >> 1) * 64, wc = (w & 1) * 64;
  const int lrow = lane & 15, lko = (lane >> 4) * 8;

  f32x4 acc[4][4];
  #pragma unroll
  for (int m = 0; m < 4; ++m)
    #pragma unroll
    for (int n = 0; n < 4; ++n) acc[m][n] = f32x4{0.f, 0.f, 0.f, 0.f};

  const u16* Ab = A + (size_t)mb * 128 * K;
  const u16* Bb = Bt + (size_t)nb * 128 * K;
  const int r0 = tid >> 2, inn = (tid & 3) * 8;
  const int l0 = (tid & ~63) * 8, l1 = ((256 + tid) & ~63) * 8;

  const int ks1 = (sb + 1) * kps;
  for (int ks = sb * kps; ks < ks1; ++ks) {
    const int k0 = ks * 32;
    __syncthreads();
    gload16(Ab + (size_t)r0 * K + k0 + inn,        lA + l0);
    gload16(Ab + (size_t)(r0 + 64) * K + k0 + inn, lA + l1);
    gload16(Bb + (size_t)r0 * K + k0 + inn,        lB + l0);
    gload16(Bb + (size_t)(r0 + 64) * K + k0 + inn, lB + l1);
    __syncthreads();
    bf16x8 af[4], bg[4];
    #pragma unroll
    for (int m = 0; m < 4; ++m)
      af[m] = *reinterpret_cast<const bf16x8*>(&lA[(wr + m * 16 + lrow) * 32 + lko]);
    #pragma unroll
    for (int n = 0; n < 4; ++n)
      bg[n] = *reinterpret_cast<const bf16x8*>(&lB[(wc + n * 16 + lrow) * 32 + lko]);
    #pragma unroll
    for (int m = 0; m < 4; ++m)
      #pragma unroll
      for (int n = 0; n < 4; ++n)
        acc[m][n] = __builtin_amdgcn_mfma_f32_16x16x32_bf16(af[m], bg[n], acc[m][n], 0, 0, 0);
  }

  float* C = Cp + (size_t)sb * M * N;
  #pragma unroll
  for (int m = 0; m < 4; ++m) {
    const int rb = mb * 128 + wr + m * 16 + (lane >> 4) * 4;
    #pragma unroll
    for (int n = 0; n < 4; ++n) {
      const int col = nb * 128 + wc + n * 16 + (lane & 15);
      #pragma unroll
      for (int j = 0; j < 4; ++j)
        __builtin_nontemporal_store(acc[m][n][j], &C[(size_t)(rb + j) * N + col]);
    }
  }
}

// ---------------------------------------------------------------------------
// Split-K reduce + bias + relu (+ cast); NT loads on the partial stream
// ---------------------------------------------------------------------------
__global__ __launch_bounds__(256) void reduce_bias_relu_bf16(
    const float* __restrict__ part, int S, size_t MN,
    const float* __restrict__ bias, int nmask, u16* __restrict__ out)
{
  for (size_t i = blockIdx.x * 256ull + threadIdx.x; i < MN; i += (size_t)gridDim.x * 256) {
    float s = 0.f;
    for (int k = 0; k < S; ++k) s += __builtin_nontemporal_load(&part[(size_t)k * MN + i]);
    s += bias[i & nmask];
    out[i] = f2bf(fmaxf(s, 0.f));
  }
}

__global__ __launch_bounds__(256) void reduce_bias_relu_f32(
    const float* __restrict__ part, int S, size_t MN,
    const float* __restrict__ bias, int nmask, float* __restrict__ out)
{
  for (size_t i = blockIdx.x * 256ull + threadIdx.x; i < MN; i += (size_t)gridDim.x * 256) {
    float s = 0.f;
    for (int k = 0; k < S; ++k) s += __builtin_nontemporal_load(&part[(size_t)k * MN + i]);
    s += bias[i & nmask];
    out[i] = fmaxf(s, 0.f);
  }
}

// ---------------------------------------------------------------------------
// Final: out[b] = h3[b,:] . W_out + b_out   (one wave per row)
// ---------------------------------------------------------------------------
__global__ __launch_bounds__(256) void final_dot(
    const float* __restrict__ h3, const float* __restrict__ Wout,
    const float* __restrict__ bout, float* __restrict__ out)
{
  const int row = blockIdx.x * 4 + (threadIdx.x >> 6);
  const int lane = threadIdx.x & 63;
  const float* hr = h3 + (size_t)row * HD3;
  float s = 0.f;
  #pragma unroll
  for (int i = 0; i < 4; ++i) s += hr[lane + i * 64] * Wout[lane + i * 64];
  #pragma unroll
  for (int off = 32; off; off >>= 1) s += __shfl_down(s, off, 64);
  if (lane == 0) out[row] = s + bout[0];
}

// ---------------------------------------------------------------------------
extern "C" void kernel_launch(void* const* d_in, const int* in_sizes, int n_in,
                              void* d_out, int out_size, void* d_ws, size_t ws_size,
                              hipStream_t stream)
{
  const int*   cat    = (const int*)  d_in[0];
  const float* num    = (const float*)d_in[1];
  const float* tables = (const float*)d_in[2];
  const float* nemb   = (const float*)d_in[3];
  const float* Wse1   = (const float*)d_in[4];
  const float* Wse2   = (const float*)d_in[5];
  const float* Wbil   = (const float*)d_in[6];
  const float* Wd1    = (const float*)d_in[7];
  const float* bd1    = (const float*)d_in[8];
  const float* Wd2    = (const float*)d_in[9];
  const float* bd2    = (const float*)d_in[10];
  const float* Wd3    = (const float*)d_in[11];
  const float* bd3    = (const float*)d_in[12];
  const float* Wout   = (const float*)d_in[13];
  const float* bout   = (const float*)d_in[14];

  char* ws = (char*)d_ws;
  // ws layout (total 311,230,464 B — round-3 proven footprint):
  u16*   hid  = (u16*)  (ws + 0ull);           // 194,248,704  bf16 [4096][23712]
  u16*   W1t  = (u16*)  (ws + 194248704ull);   //  48,562,176  bf16 [1024][23712]
  float* part = (float*)(ws + 242810880ull);   //  67,108,864  f32 splitK partials (S<=4)
  u16*   W2t  = (u16*)  (ws + 309919744ull);   //   1,048,576  bf16 [512][1024]
  u16*   W3t  = (u16*)  (ws + 310968320ull);   //     262,144  bf16 [256][512]
  // dead-hid region reuse (hid consumed by gemm1 before these are written):
  u16*   h1b  = (u16*)  (ws + 0ull);           //   8,388,608  bf16 [4096][1024]
  u16*   h2b  = (u16*)  (ws + 8388608ull);     //   4,194,304  bf16 [4096][512]
  float* h3f  = (float*)(ws + 12582912ull);    //   4,194,304  f32  [4096][256]

  transpose_cast<<<dim3(KHID / 32, HD1 / 32), 256, 0, stream>>>(Wd1, W1t, KHID, HD1);
  transpose_cast<<<dim3(HD1 / 32, HD2 / 32), 256, 0, stream>>>(Wd2, W2t, HD1, HD2);
  transpose_cast<<<dim3(HD2 / 32, HD3 / 32), 256, 0, stream>>>(Wd3, W3t, HD2, HD3);
  fuse_front<<<BATCH, 256, 0, stream>>>(cat, num, tables, nemb, Wse1, Wse2, Wbil, hid);

  // layer 1: [4096 x 23712] @ [23712 x 1024], 256^2 pipelined,
  // split-K=4 uneven (186/186/186/183 K-units), 1D grid 256 = exact CU fill
  gemm8_bf16<<<256, 512, 0, stream>>>(hid, W1t, part, BATCH, HD1, KHID, 741, 186);
  reduce_bias_relu_bf16<<<2048, 256, 0, stream>>>(part, 4, (size_t)BATCH * HD1, bd1, HD1 - 1, h1b);

  // layer 2: [4096 x 1024] @ [1024 x 512], split-K=2 (32 = 2*16)
  gemm_bf16<<<dim3(BATCH / 128, HD2 / 128, 2), 256, 0, stream>>>(h1b, W2t, part, BATCH, HD2, HD1, 16);
  reduce_bias_relu_bf16<<<2048, 256, 0, stream>>>(part, 2, (size_t)BATCH * HD2, bd2, HD2 - 1, h2b);

  // layer 3: [4096 x 512] @ [512 x 256], split-K=4 (16 = 4*4)
  gemm_bf16<<<dim3(BATCH / 128, HD3 / 128, 4), 256, 0, stream>>>(h2b, W3t, part, BATCH, HD3, HD2, 4);
  reduce_bias_relu_f32<<<2048, 256, 0, stream>>>(part, 4, (size_t)BATCH * HD3, bd3, HD3 - 1, h3f);

  final_dot<<<BATCH / 4, 256, 0, stream>>>(h3f, Wout, bout, (float*)d_out);
}

// Round 6
// 381.469 us; speedup vs baseline: 5.9850x; 1.0453x over previous
//
#include <hip/hip_runtime.h>

typedef unsigned short u16;
typedef __attribute__((ext_vector_type(8))) __bf16 bf16x8;
typedef __attribute__((ext_vector_type(4))) float f32x4;

#define NF    39
#define NNUM  13
#define NCAT  26
#define VOC   100000
#define NPAIR 741
#define KHID  23712   /* 2*741*16 */
#define BATCH 4096
#define HD1   1024
#define HD2   512
#define HD3   256

__device__ __forceinline__ u16 f2bf(float f) {
  unsigned u = __builtin_bit_cast(unsigned, f);
  return (u16)((u + 0x7fffu + ((u >> 16) & 1u)) >> 16);   // RNE
}

__device__ __forceinline__ void gload16(const void* g, void* l) {
  __builtin_amdgcn_global_load_lds((const __attribute__((address_space(1))) void*)g,
                                   (__attribute__((address_space(3))) void*)l, 16, 0, 0);
}

// ---------------------------------------------------------------------------
// Front end: gather + SE + bilinear proj + pairwise products -> hid bf16 [B][23712]
// ---------------------------------------------------------------------------
__global__ __launch_bounds__(256) void fuse_front(
    const int* __restrict__ cat, const float* __restrict__ num,
    const float* __restrict__ tables, const float* __restrict__ nemb,
    const float* __restrict__ Wse1, const float* __restrict__ Wse2,
    const float* __restrict__ Wbil, u16* __restrict__ hid)
{
  __shared__ float xs[NF][16];
  __shared__ float wb[NF][16][16];   // [f][e][d]
  __shared__ float pr[NF][16];       // proj
  __shared__ float Zs[NF], Ts[NNUM], As[NF];
  __shared__ unsigned char pis[NPAIR], pjs[NPAIR];

  const int b = blockIdx.x;
  const int tid = threadIdx.x;

  for (int i = tid; i < NF * 256; i += 256) ((float*)wb)[i] = Wbil[i];

  for (int t = tid; t < NNUM * 16; t += 256) {
    int f = t >> 4, e = t & 15;
    xs[f][e] = num[b * NNUM + f] * nemb[t];
  }
  for (int t = tid; t < NCAT * 16; t += 256) {
    int c = t >> 4, e = t & 15;
    int cv = cat[b * NCAT + c];
    xs[NNUM + c][e] = tables[((size_t)c * VOC + cv) * 16 + e];
  }
  for (int p = tid; p < NPAIR; p += 256) {
    int i = 0, rs = 0;
    while (p >= rs + (NF - 1 - i)) { rs += NF - 1 - i; ++i; }
    pis[p] = (unsigned char)i;
    pjs[p] = (unsigned char)(i + 1 + (p - rs));
  }
  __syncthreads();

  if (tid < NF) {
    float s = 0.f;
    #pragma unroll
    for (int e = 0; e < 16; ++e) s += xs[tid][e];
    Zs[tid] = s * (1.f / 16.f);
  }
  __syncthreads();
  if (tid < NNUM) {
    float s = 0.f;
    for (int f = 0; f < NF; ++f) s += Zs[f] * Wse1[f * NNUM + tid];
    Ts[tid] = fmaxf(s, 0.f);
  }
  __syncthreads();
  if (tid < NF) {
    float s = 0.f;
    for (int r = 0; r < NNUM; ++r) s += Ts[r] * Wse2[r * NF + tid];
    As[tid] = fmaxf(s, 0.f);
  }
  for (int t = tid; t < NF * 16; t += 256) {
    int f = t >> 4, d = t & 15;
    float s = 0.f;
    #pragma unroll
    for (int e = 0; e < 16; ++e) s += xs[f][e] * wb[f][e][d];
    pr[f][d] = s;
  }
  __syncthreads();

  u16* hr = hid + (size_t)b * KHID;
  for (int idx = tid; idx < NPAIR * 16; idx += 256) {
    int p = idx >> 4, e = idx & 15;
    int i = pis[p], j = pjs[p];
    float bv = pr[i][e] * xs[j][e];
    hr[NPAIR * 16 + idx] = f2bf(bv);
    hr[idx] = f2bf(As[i] * As[j] * bv);
  }
}

// ---------------------------------------------------------------------------
// Transpose + cast: in f32 [K][N] -> out bf16 [N][K]
// ---------------------------------------------------------------------------
__global__ __launch_bounds__(256) void transpose_cast(
    const float* __restrict__ in, u16* __restrict__ out, int K, int N)
{
  __shared__ float t[32][33];
  const int k0 = blockIdx.x * 32, n0 = blockIdx.y * 32;
  const int c = threadIdx.x & 31, r = threadIdx.x >> 5;
  #pragma unroll
  for (int it = 0; it < 4; ++it)
    t[r + it * 8][c] = in[(size_t)(k0 + r + it * 8) * N + n0 + c];
  __syncthreads();
  #pragma unroll
  for (int it = 0; it < 4; ++it)
    out[(size_t)(n0 + r + it * 8) * K + k0 + c] = f2bf(t[c][r + it * 8]);
}

// ---------------------------------------------------------------------------
// 256x256 8-wave pipelined bf16 GEMM. 2D-grouped XCD swizzle (A fetched once
// chip-wide) + T2 LDS swizzle + T3/T4 counted vmcnt 4-slot ring + T5 setprio.
// One barrier per phase (round-5 proven): at barrier(t) every wave has
// data-complete its phase-(t-1) ds_reads, so staging into slot
// (t+3)&3 == (t-1)&3 after the barrier is race-free; vmcnt(8) before the
// barrier proves slot t&3 fully arrived.
// ---------------------------------------------------------------------------
__global__ __launch_bounds__(512, 2) void gemm8_bf16(
    const u16* __restrict__ A, const u16* __restrict__ Bt,
    float* __restrict__ Cp, int M, int N, int K, int totku, int kpb)
{
  __shared__ __align__(16) u16 lds[4 * 16384];   // 128 KiB

  const int tid = threadIdx.x;
  const int wid = tid >> 6, lane = tid & 63;

  // 2D-grouped bijective XCD swizzle (assumes dispatch d -> XCD d%8):
  // XCD x owns mb in {4*(x&3)..+3}, sb in {2*(x>>2), 2*(x>>2)+1}, all nb.
  // -> each A-strip's 4 nb-readers are co-XCD (A fetched once chip-wide);
  //    each B-strip read by 4 co-XCD mb-blocks (B fetched 4x chip-wide).
  const int d = blockIdx.x;
  const int x = d & 7;                         // XCD
  const int j = d >> 3;                        // [0,32)
  const int mb = ((x & 3) << 2) | (j & 3);     // [0,16)
  const int nb = (j >> 2) & 3;                 // [0,4)
  const int sb = ((x >> 2) << 1) | (j >> 4);   // [0,4)

  const int ks0 = sb * kpb;
  const int kunits = (totku - ks0 < kpb) ? (totku - ks0) : kpb;

  const int wm = wid >> 2, wn = wid & 3;        // 2M x 4N waves
  const int lrow = lane & 15, c0 = lane >> 4;

  // staging addresses (inverse-swizzled global source, linear LDS dest)
  const int rA = tid >> 2;
  const int csrc = (tid & 3) ^ ((rA >> 1) & 3);
  const u16* pA = A  + (size_t)((size_t)mb * 256 + rA) * K + (size_t)ks0 * 32 + csrc * 8;
  const u16* pB = Bt + (size_t)((size_t)nb * 256 + rA) * K + (size_t)ks0 * 32 + csrc * 8;
  const size_t rowskip = (size_t)128 * K;
  u16* dA = lds + wid * 512;
  u16* dB = lds + 8192 + wid * 512;

  // swizzled read offsets (loop-invariant per lane)
  int offA[8], offB[4];
  #pragma unroll
  for (int m = 0; m < 8; ++m) {
    int r = wm * 128 + m * 16 + lrow;
    offA[m] = r * 32 + ((c0 ^ ((r >> 1) & 3)) << 3);
  }
  #pragma unroll
  for (int n = 0; n < 4; ++n) {
    int r = wn * 64 + n * 16 + lrow;
    offB[n] = 8192 + r * 32 + ((c0 ^ ((r >> 1) & 3)) << 3);
  }

  f32x4 acc[8][4];
  #pragma unroll
  for (int m = 0; m < 8; ++m)
    #pragma unroll
    for (int n = 0; n < 4; ++n) acc[m][n] = f32x4{0.f, 0.f, 0.f, 0.f};

  // prologue: stage units 0,1,2 into slots 0,1,2 (12 loads/thread in flight)
  #pragma unroll
  for (int u = 0; u < 3; ++u) {
    const u16* a = pA + u * 32;
    const u16* b = pB + u * 32;
    u16* da = dA + u * 16384;
    u16* db = dB + u * 16384;
    gload16(a, da);            gload16(a + rowskip, da + 4096);
    gload16(b, db);            gload16(b + rowskip, db + 4096);
  }

  for (int t = 0; t < kunits; ++t) {
    // in flight: units t,t+1,t+2 (12 loads) -> wait oldest 4 (unit t), keep 8
    asm volatile("s_waitcnt vmcnt(8)" ::: "memory");
    __builtin_amdgcn_s_barrier();
    __builtin_amdgcn_sched_barrier(0);

    // stage unit t+3 into slot (t+3)&3 == (t-1)&3 (read-complete by barrier)
    {
      int su = (t + 3 < kunits) ? (t + 3) : (kunits - 1);
      const u16* a = pA + (size_t)su * 32;
      const u16* b = pB + (size_t)su * 32;
      int so = ((t + 3) & 3) * 16384;
      u16* da = dA + so;
      u16* db = dB + so;
      gload16(a, da);          gload16(a + rowskip, da + 4096);
      gload16(b, db);          gload16(b + rowskip, db + 4096);
    }

    const u16* sl = lds + (t & 3) * 16384;
    bf16x8 af[8], bg[4];
    #pragma unroll
    for (int m = 0; m < 8; ++m) af[m] = *reinterpret_cast<const bf16x8*>(sl + offA[m]);
    #pragma unroll
    for (int n = 0; n < 4; ++n) bg[n] = *reinterpret_cast<const bf16x8*>(sl + offB[n]);

    __builtin_amdgcn_s_setprio(1);
    #pragma unroll
    for (int m = 0; m < 8; ++m)
      #pragma unroll
      for (int n = 0; n < 4; ++n)
        acc[m][n] = __builtin_amdgcn_mfma_f32_16x16x32_bf16(af[m], bg[n], acc[m][n], 0, 0, 0);
    __builtin_amdgcn_s_setprio(0);

    __builtin_amdgcn_sched_barrier(0);
    // no trailing barrier: next phase's barrier provides the cross-wave sync
  }

  // epilogue: write f32 partials (NT: keep the partial stream out of L2/L3)
  float* C = Cp + (size_t)sb * M * N;
  #pragma unroll
  for (int m = 0; m < 8; ++m) {
    const int rb = mb * 256 + wm * 128 + m * 16 + (lane >> 4) * 4;
    #pragma unroll
    for (int n = 0; n < 4; ++n) {
      const int col = nb * 256 + wn * 64 + n * 16 + (lane & 15);
      #pragma unroll
      for (int j2 = 0; j2 < 4; ++j2)
        __builtin_nontemporal_store(acc[m][n][j2], &C[(size_t)(rb + j2) * N + col]);
    }
  }
}

// ---------------------------------------------------------------------------
// 128x128 m97-structure GEMM for the small layers 2/3
// ---------------------------------------------------------------------------
__global__ __launch_bounds__(256) void gemm_bf16(
    const u16* __restrict__ A, const u16* __restrict__ Bt,
    float* __restrict__ Cp, int M, int N, int K, int kps)
{
  __shared__ __align__(16) u16 lA[128 * 32];
  __shared__ __align__(16) u16 lB[128 * 32];
  const int tid = threadIdx.x;
  const int mb = blockIdx.x, nb = blockIdx.y, sb = blockIdx.z;
  const int w = tid >> 6, lane = tid & 63;
  const int wr = (w >> 1) * 64, wc = (w & 1) * 64;
  const int lrow = lane & 15, lko = (lane >> 4) * 8;

  f32x4 acc[4][4];
  #pragma unroll
  for (int m = 0; m < 4; ++m)
    #pragma unroll
    for (int n = 0; n < 4; ++n) acc[m][n] = f32x4{0.f, 0.f, 0.f, 0.f};

  const u16* Ab = A + (size_t)mb * 128 * K;
  const u16* Bb = Bt + (size_t)nb * 128 * K;
  const int r0 = tid >> 2, inn = (tid & 3) * 8;
  const int l0 = (tid & ~63) * 8, l1 = ((256 + tid) & ~63) * 8;

  const int ks1 = (sb + 1) * kps;
  for (int ks = sb * kps; ks < ks1; ++ks) {
    const int k0 = ks * 32;
    __syncthreads();
    gload16(Ab + (size_t)r0 * K + k0 + inn,        lA + l0);
    gload16(Ab + (size_t)(r0 + 64) * K + k0 + inn, lA + l1);
    gload16(Bb + (size_t)r0 * K + k0 + inn,        lB + l0);
    gload16(Bb + (size_t)(r0 + 64) * K + k0 + inn, lB + l1);
    __syncthreads();
    bf16x8 af[4], bg[4];
    #pragma unroll
    for (int m = 0; m < 4; ++m)
      af[m] = *reinterpret_cast<const bf16x8*>(&lA[(wr + m * 16 + lrow) * 32 + lko]);
    #pragma unroll
    for (int n = 0; n < 4; ++n)
      bg[n] = *reinterpret_cast<const bf16x8*>(&lB[(wc + n * 16 + lrow) * 32 + lko]);
    #pragma unroll
    for (int m = 0; m < 4; ++m)
      #pragma unroll
      for (int n = 0; n < 4; ++n)
        acc[m][n] = __builtin_amdgcn_mfma_f32_16x16x32_bf16(af[m], bg[n], acc[m][n], 0, 0, 0);
  }

  float* C = Cp + (size_t)sb * M * N;
  #pragma unroll
  for (int m = 0; m < 4; ++m) {
    const int rb = mb * 128 + wr + m * 16 + (lane >> 4) * 4;
    #pragma unroll
    for (int n = 0; n < 4; ++n) {
      const int col = nb * 128 + wc + n * 16 + (lane & 15);
      #pragma unroll
      for (int j = 0; j < 4; ++j)
        __builtin_nontemporal_store(acc[m][n][j], &C[(size_t)(rb + j) * N + col]);
    }
  }
}

// ---------------------------------------------------------------------------
// Split-K reduce + bias + relu (+ cast); NT loads on the partial stream
// ---------------------------------------------------------------------------
__global__ __launch_bounds__(256) void reduce_bias_relu_bf16(
    const float* __restrict__ part, int S, size_t MN,
    const float* __restrict__ bias, int nmask, u16* __restrict__ out)
{
  for (size_t i = blockIdx.x * 256ull + threadIdx.x; i < MN; i += (size_t)gridDim.x * 256) {
    float s = 0.f;
    for (int k = 0; k < S; ++k) s += __builtin_nontemporal_load(&part[(size_t)k * MN + i]);
    s += bias[i & nmask];
    out[i] = f2bf(fmaxf(s, 0.f));
  }
}

__global__ __launch_bounds__(256) void reduce_bias_relu_f32(
    const float* __restrict__ part, int S, size_t MN,
    const float* __restrict__ bias, int nmask, float* __restrict__ out)
{
  for (size_t i = blockIdx.x * 256ull + threadIdx.x; i < MN; i += (size_t)gridDim.x * 256) {
    float s = 0.f;
    for (int k = 0; k < S; ++k) s += __builtin_nontemporal_load(&part[(size_t)k * MN + i]);
    s += bias[i & nmask];
    out[i] = fmaxf(s, 0.f);
  }
}

// ---------------------------------------------------------------------------
// Final: out[b] = h3[b,:] . W_out + b_out   (one wave per row)
// ---------------------------------------------------------------------------
__global__ __launch_bounds__(256) void final_dot(
    const float* __restrict__ h3, const float* __restrict__ Wout,
    const float* __restrict__ bout, float* __restrict__ out)
{
  const int row = blockIdx.x * 4 + (threadIdx.x >> 6);
  const int lane = threadIdx.x & 63;
  const float* hr = h3 + (size_t)row * HD3;
  float s = 0.f;
  #pragma unroll
  for (int i = 0; i < 4; ++i) s += hr[lane + i * 64] * Wout[lane + i * 64];
  #pragma unroll
  for (int off = 32; off; off >>= 1) s += __shfl_down(s, off, 64);
  if (lane == 0) out[row] = s + bout[0];
}

// ---------------------------------------------------------------------------
extern "C" void kernel_launch(void* const* d_in, const int* in_sizes, int n_in,
                              void* d_out, int out_size, void* d_ws, size_t ws_size,
                              hipStream_t stream)
{
  const int*   cat    = (const int*)  d_in[0];
  const float* num    = (const float*)d_in[1];
  const float* tables = (const float*)d_in[2];
  const float* nemb   = (const float*)d_in[3];
  const float* Wse1   = (const float*)d_in[4];
  const float* Wse2   = (const float*)d_in[5];
  const float* Wbil   = (const float*)d_in[6];
  const float* Wd1    = (const float*)d_in[7];
  const float* bd1    = (const float*)d_in[8];
  const float* Wd2    = (const float*)d_in[9];
  const float* bd2    = (const float*)d_in[10];
  const float* Wd3    = (const float*)d_in[11];
  const float* bd3    = (const float*)d_in[12];
  const float* Wout   = (const float*)d_in[13];
  const float* bout   = (const float*)d_in[14];

  char* ws = (char*)d_ws;
  // ws layout (total 311,230,464 B — round-3 proven footprint):
  u16*   hid  = (u16*)  (ws + 0ull);           // 194,248,704  bf16 [4096][23712]
  u16*   W1t  = (u16*)  (ws + 194248704ull);   //  48,562,176  bf16 [1024][23712]
  float* part = (float*)(ws + 242810880ull);   //  67,108,864  f32 splitK partials (S<=4)
  u16*   W2t  = (u16*)  (ws + 309919744ull);   //   1,048,576  bf16 [512][1024]
  u16*   W3t  = (u16*)  (ws + 310968320ull);   //     262,144  bf16 [256][512]
  // dead-hid region reuse (hid consumed by gemm1 before these are written):
  u16*   h1b  = (u16*)  (ws + 0ull);           //   8,388,608  bf16 [4096][1024]
  u16*   h2b  = (u16*)  (ws + 8388608ull);     //   4,194,304  bf16 [4096][512]
  float* h3f  = (float*)(ws + 12582912ull);    //   4,194,304  f32  [4096][256]

  transpose_cast<<<dim3(KHID / 32, HD1 / 32), 256, 0, stream>>>(Wd1, W1t, KHID, HD1);
  transpose_cast<<<dim3(HD1 / 32, HD2 / 32), 256, 0, stream>>>(Wd2, W2t, HD1, HD2);
  transpose_cast<<<dim3(HD2 / 32, HD3 / 32), 256, 0, stream>>>(Wd3, W3t, HD2, HD3);
  fuse_front<<<BATCH, 256, 0, stream>>>(cat, num, tables, nemb, Wse1, Wse2, Wbil, hid);

  // layer 1: [4096 x 23712] @ [23712 x 1024], 256^2 pipelined,
  // split-K=4 uneven (186/186/186/183 K-units), 1D grid 256 = exact CU fill
  gemm8_bf16<<<256, 512, 0, stream>>>(hid, W1t, part, BATCH, HD1, KHID, 741, 186);
  reduce_bias_relu_bf16<<<2048, 256, 0, stream>>>(part, 4, (size_t)BATCH * HD1, bd1, HD1 - 1, h1b);

  // layer 2: [4096 x 1024] @ [1024 x 512], split-K=2 (32 = 2*16)
  gemm_bf16<<<dim3(BATCH / 128, HD2 / 128, 2), 256, 0, stream>>>(h1b, W2t, part, BATCH, HD2, HD1, 16);
  reduce_bias_relu_bf16<<<2048, 256, 0, stream>>>(part, 2, (size_t)BATCH * HD2, bd2, HD2 - 1, h2b);

  // layer 3: [4096 x 512] @ [512 x 256], split-K=4 (16 = 4*4)
  gemm_bf16<<<dim3(BATCH / 128, HD3 / 128, 4), 256, 0, stream>>>(h2b, W3t, part, BATCH, HD3, HD2, 4);
  reduce_bias_relu_f32<<<2048, 256, 0, stream>>>(part, 4, (size_t)BATCH * HD3, bd3, HD3 - 1, h3f);

  final_dot<<<BATCH / 4, 256, 0, stream>>>(h3f, Wout, bout, (float*)d_out);
}